// Round 5
// baseline (361.625 us; speedup 1.0000x reference)
//
#include <hip/hip_runtime.h>
#include <hip/hip_bf16.h>
#include <stdint.h>

#define BATCH 8
#define SEQ   4096
#define EMB   1024
#define HD    128
#define NROWS 32768

typedef __attribute__((ext_vector_type(8))) short short8;
typedef __attribute__((ext_vector_type(4))) float f32x4;

__device__ inline unsigned short f2bf(float f) {
    union { float f; unsigned int u; } c; c.f = f;
    unsigned int u = c.u;
    unsigned int r = (u + 0x7fffu + ((u >> 16) & 1u)) >> 16;
    return (unsigned short)r;
}
__device__ inline float bf2f(unsigned short u) {
    union { unsigned int i; float f; } c; c.i = ((unsigned int)u) << 16; return c.f;
}
__device__ inline unsigned int pkbf(float a, float b) {
    __hip_bfloat162 h = __float22bfloat162_rn(make_float2(a, b));
    union { __hip_bfloat162 h; unsigned int u; } c; c.h = h; return c.u;
}

#define GLDS16(gp, lp) __builtin_amdgcn_global_load_lds( \
    (const __attribute__((address_space(1))) void*)(gp), \
    (__attribute__((address_space(3))) void*)(lp), 16, 0, 0)

// ---- stream-K work decomposition (32-key items) ---------------------------
// item = (b, qt, kv32); per batch: sum_qt 4(qt+1) = 2112; total 16896.
// 768 blocks x exactly 22 items. chunk = (rank&7)*96 + rank/8 -> each XCD
// owns exactly one batch (K+V+Q ~3MB, L2-resident).
__device__ inline void decomp(int it, int& b, int& qt, int& kv) {
    b = it / 2112;
    int r = it - b * 2112;
    int q = (int)((__builtin_sqrtf(2.0f * (float)r + 1.0f) - 1.0f) * 0.5f);
    while (2 * (q + 1) * (q + 2) <= r) ++q;
    while (2 * q * (q + 1) > r) --q;
    qt = q;
    kv = r - 2 * q * (q + 1);
}
// overflow-slot base per batch; seg-width bands; 112/batch
__device__ inline int base1(int qt) {
    if (qt < 5)  return qt;
    if (qt < 11) return 5 + 2 * (qt - 5);
    if (qt < 16) return 17 + 3 * (qt - 11);
    if (qt < 22) return 32 + 4 * (qt - 16);
    if (qt < 27) return 56 + 5 * (qt - 22);
    return 81 + 6 * (qt - 27);
}

// ---------------------------------------------------------------------------
// prep: wt[n][k] = bf16(W[k][h]) for n = sel*128+h. 384 blocks, one row each.
// ---------------------------------------------------------------------------
__global__ __launch_bounds__(256) void prep_kernel(
    const float* __restrict__ Wq, const float* __restrict__ bq,
    const float* __restrict__ Wk, const float* __restrict__ bk,
    const float* __restrict__ Wv, const float* __restrict__ bv,
    unsigned short* __restrict__ wt, float* __restrict__ biasc)
{
    const int n = blockIdx.x;           // 0..383
    const int sel = n >> 7, h = n & 127;
    const float* W = (sel == 0) ? Wq : (sel == 1) ? Wk : Wv;
    const int tid = threadIdx.x;
    const int k0 = tid * 4;
    union { unsigned short us[4]; uint2 v; } pk;
#pragma unroll
    for (int u = 0; u < 4; ++u) pk.us[u] = f2bf(W[(size_t)(k0 + u) * HD + h]);
    *(uint2*)&wt[(size_t)n * EMB + k0] = pk.v;
    if (tid == 0) {
        const float* bp = (sel == 0) ? bq : (sel == 1) ? bk : bv;
        biasc[n] = bp[h];
    }
}

// ---------------------------------------------------------------------------
// gemm_qkv v2: fused QKV. 256 blocks x 128 rows x all 384 cols; 12 waves
// (768 thr), wave tile 64 rows x 64 cols, acc[4][4].
// ---------------------------------------------------------------------------
__global__ __launch_bounds__(768, 3) void gemm_qkv(
    const float* __restrict__ x, const unsigned short* __restrict__ wt,
    const float* __restrict__ biasc,
    unsigned short* __restrict__ q, unsigned short* __restrict__ kOut,
    unsigned short* __restrict__ vt)
{
    const int m0  = blockIdx.x * 128;
    const int tid = threadIdx.x;
    const int wave = tid >> 6, lane = tid & 63;
    const int quad = lane >> 4, l15 = lane & 15;
    const int wm = (wave >= 6) ? 1 : 0;      // 2 M-waves x 6 N-waves
    const int wn = wave - wm * 6;            // 0..5, 64 cols each

    __shared__ __align__(16) unsigned short As[2][128][40];   // +8 pad
    __shared__ __align__(16) unsigned short Bs[2][12288];     // [384][32] swizzled

    f32x4 acc[4][4];
#pragma unroll
    for (int i = 0; i < 4; ++i)
#pragma unroll
        for (int j = 0; j < 4; ++j) acc[i][j] = (f32x4){0.f, 0.f, 0.f, 0.f};

    const int aactive = (tid < 512);
    const int arow = tid >> 3, akc = (tid & 7) * 4;
    float4 aR0, aR1;

#define LOAD_A(kt)                                                          \
    if (aactive) {                                                          \
        aR0 = *(const float4*)(x + (size_t)(m0 + arow) * EMB + (kt) * 32 + akc);        \
        aR1 = *(const float4*)(x + (size_t)(m0 + arow + 64) * EMB + (kt) * 32 + akc);   \
    }
#define WRITE_A(buf)                                                        \
    if (aactive) {                                                          \
        union { unsigned short us[4]; uint2 v; } p0, p1;                    \
        p0.us[0] = f2bf(aR0.x); p0.us[1] = f2bf(aR0.y);                     \
        p0.us[2] = f2bf(aR0.z); p0.us[3] = f2bf(aR0.w);                     \
        *(uint2*)&As[buf][arow][akc] = p0.v;                                \
        p1.us[0] = f2bf(aR1.x); p1.us[1] = f2bf(aR1.y);                     \
        p1.us[2] = f2bf(aR1.z); p1.us[3] = f2bf(aR1.w);                     \
        *(uint2*)&As[buf][arow + 64][akc] = p1.v;                           \
    }
#define STAGE_B(kt, buf)                                                    \
    {                                                                       \
        _Pragma("unroll")                                                   \
        for (int g = 0; g < 2; ++g) {                                       \
            int s0 = (g * 12 + wave) * 64;                                  \
            int s  = s0 + lane;                                             \
            int n  = s >> 2, c = (s & 3) ^ (n & 3);                         \
            GLDS16(wt + (size_t)n * EMB + (kt) * 32 + c * 8,                \
                   &Bs[buf][s0 * 8]);                                       \
        }                                                                   \
    }

    LOAD_A(0); STAGE_B(0, 0); WRITE_A(0);
    int cur = 0;

    for (int kt = 0; kt < 32; ++kt) {
        __syncthreads();
        if (kt < 31) { LOAD_A(kt + 1); STAGE_B(kt + 1, cur ^ 1); }
        short8 af[4], bw[4];
#pragma unroll
        for (int mj = 0; mj < 4; ++mj)
            af[mj] = *(const short8*)&As[cur][wm * 64 + mj * 16 + l15][quad * 8];
#pragma unroll
        for (int ni = 0; ni < 4; ++ni) {
            int n = wn * 64 + ni * 16 + l15;
            bw[ni] = *(const short8*)&Bs[cur][n * 32 + ((quad ^ (n & 3)) << 3)];
        }
#pragma unroll
        for (int ni = 0; ni < 4; ++ni)
#pragma unroll
            for (int mj = 0; mj < 4; ++mj)
                acc[ni][mj] = __builtin_amdgcn_mfma_f32_16x16x32_bf16(
                    bw[ni], af[mj], acc[ni][mj], 0, 0, 0);
        if (kt < 31) WRITE_A(cur ^ 1);
        cur ^= 1;
    }

    const float qscale = 0.08838834764831845f * 1.4426950408889634f;
    const int bb = m0 >> 12;
    const int t0 = m0 & 4095;
    const int mrow0 = m0 + wm * 64;
    const int tl0   = t0 + wm * 64;
#pragma unroll
    for (int ni = 0; ni < 4; ++ni) {
        int colbase = wn * 64 + ni * 16;
        int sel = colbase >> 7;
        int c0 = colbase + quad * 4;
        float4 bv4 = *(const float4*)&biasc[c0];
#pragma unroll
        for (int mj = 0; mj < 4; ++mj) {
            int m = mrow0 + mj * 16 + l15;
            if (sel == 0) {
                union { unsigned short us[4]; uint2 v; } pk;
#pragma unroll
                for (int j = 0; j < 4; ++j)
                    pk.us[j] = f2bf((acc[ni][mj][j] + ((const float*)&bv4)[j]) * qscale);
                *(uint2*)&q[(size_t)m * HD + (c0 & 127)] = pk.v;
            } else if (sel == 1) {
                union { unsigned short us[4]; uint2 v; } pk;
#pragma unroll
                for (int j = 0; j < 4; ++j)
                    pk.us[j] = f2bf(acc[ni][mj][j] + ((const float*)&bv4)[j]);
                *(uint2*)&kOut[(size_t)m * HD + (c0 & 127)] = pk.v;
            } else {
#pragma unroll
                for (int j = 0; j < 4; ++j) {
                    int h = (c0 & 127) + j;
                    vt[((size_t)(bb * 128 + h)) * SEQ + tl0 + mj * 16 + l15] =
                        f2bf(acc[ni][mj][j] + ((const float*)&bv4)[j]);
                }
            }
        }
    }
#undef LOAD_A
#undef WRITE_A
#undef STAGE_B
}

// ---------------------------------------------------------------------------
// attn v5: stream-K flash attention, 32-key items, 768 blocks x 256 thr.
// Changes vs v4 (inferred attn ~73us, chain still latency-bound):
//  - __launch_bounds__(256,4): VGPR<=128 + LDS 32KB allow 4 blocks/CU
//    (16 waves, 4 contexts/SIMD, +33% latency overlap vs v4's 3).
//  - decomp() removed from the loop head (sqrt+divides+whiles fed STAGE
//    addressing serially); incremental (b,qt,kv) advance instead.
//  - softmax halves pipelined: smax0 -> bperm0 -> smax1 -> bperm1 -> PV,
//    hiding bperm DS latency under smax VALU.
// ---------------------------------------------------------------------------
__global__ __launch_bounds__(256, 4) void attn_kernel(
    const unsigned short* __restrict__ q, const unsigned short* __restrict__ k,
    const unsigned short* __restrict__ vt, float* __restrict__ out,
    float* __restrict__ Oseg, float2* __restrict__ ml)
{
    const int rank  = blockIdx.x;                       // 0..767
    const int chunk = (rank & 7) * 96 + (rank >> 3);    // XCD-contiguous
    const int start = chunk * 22;
    const int iend  = start + 22;

    const int tid  = threadIdx.x;
    const int wave = tid >> 6, lane = tid & 63;
    const int quad = lane >> 4, l15 = lane & 15;

    __shared__ __align__(16) unsigned short Ks[2][4096];  // [32 key][16 ch8 sw]
    __shared__ __align__(16) unsigned short Vs[2][4096];  // [128 h][4 ch8 sw]

    const int bpa0 = (l15 + 16 * ((2 * quad) & 3)) * 4;   // bpermute byte addrs
    const int bpa1 = (l15 + 16 * ((2 * quad + 1) & 3)) * 4;

#define STAGE_KV(b_, kv_, buf_)                                              \
    {                                                                        \
        const size_t kb0 = (size_t)(b_) * SEQ + (kv_) * 32;                  \
        const size_t vb0 = (size_t)(b_) * HD * SEQ + (kv_) * 32;             \
        _Pragma("unroll")                                                    \
        for (int g = 0; g < 2; ++g) {                                        \
            int s0 = (g * 4 + wave) * 64;                                    \
            int s  = s0 + lane;                                              \
            int key = s >> 4, c = (s & 15) ^ (key & 15);                     \
            GLDS16(k + (kb0 + key) * HD + c * 8, &Ks[buf_][s0 * 8]);         \
        }                                                                    \
        _Pragma("unroll")                                                    \
        for (int g = 0; g < 2; ++g) {                                        \
            int s0 = (g * 4 + wave) * 64;                                    \
            int s  = s0 + lane;                                              \
            int h = s >> 2, c = (s & 3) ^ ((h >> 2) & 3);                    \
            GLDS16(vt + vb0 + (size_t)h * SEQ + c * 8, &Vs[buf_][s0 * 8]);   \
        }                                                                    \
    }

    int b, qt, kv;
    decomp(start, b, qt, kv);

    short8 qf[2][4];
    f32x4  o[2][8];
    float  m_r[2], l_r[2];
    int    qrow0 = 0;

#define CTX_INIT(b_, q_)                                                     \
    {                                                                        \
        qrow0 = (q_) * 128 + wave * 32;                                      \
        const size_t qoff = (size_t)(b_) * SEQ + qrow0;                      \
        _Pragma("unroll")                                                    \
        for (int mi = 0; mi < 2; ++mi)                                       \
            _Pragma("unroll")                                                \
            for (int kh = 0; kh < 4; ++kh)                                   \
                qf[mi][kh] = *(const short8*)(q + (qoff + mi * 16 + l15) * HD + kh * 32 + quad * 8); \
        _Pragma("unroll")                                                    \
        for (int mi = 0; mi < 2; ++mi) {                                     \
            _Pragma("unroll")                                                \
            for (int hi = 0; hi < 8; ++hi) o[mi][hi] = (f32x4){0.f, 0.f, 0.f, 0.f}; \
            m_r[mi] = -1e30f; l_r[mi] = 0.f;                                 \
        }                                                                    \
    }

#define CTX_FLUSH()                                                          \
    {                                                                        \
        const int I0 = b * 2112 + 2 * qt * (qt + 1);                         \
        const int j  = chunk - I0 / 22;                                      \
        const int rr = wave * 32;                                            \
        float* obase;                                                        \
        if (j == 0) obase = out + ((size_t)b * SEQ + qrow0) * HD;            \
        else obase = Oseg + ((size_t)(b * 112 + base1(qt) + j - 1) * 128 + rr) * HD; \
        const size_t mlb = ((size_t)(b * 32 + qt) * 7 + j) * 128 + rr;       \
        _Pragma("unroll")                                                    \
        for (int mi = 0; mi < 2; ++mi) {                                     \
            if (quad == 0) ml[mlb + mi * 16 + l15] = make_float2(m_r[mi], l_r[mi]); \
            _Pragma("unroll")                                                \
            for (int hi = 0; hi < 8; ++hi)                                   \
                *(f32x4*)&obase[(size_t)(mi * 16 + l15) * HD + hi * 16 + quad * 4] = o[mi][hi]; \
        }                                                                    \
    }

// wave-parallel softmax for one mi half; writes pk_, updates m_r/l_r/o
#define SMAX(sarr, mi_, pk_)                                                 \
    {                                                                        \
        float mx = fmaxf(fmaxf(fmaxf(sarr[0][0], sarr[0][1]),               \
                               fmaxf(sarr[0][2], sarr[0][3])),              \
                         fmaxf(fmaxf(sarr[1][0], sarr[1][1]),               \
                               fmaxf(sarr[1][2], sarr[1][3])));             \
        mx = fmaxf(mx, __shfl_xor(mx, 16));                                  \
        mx = fmaxf(mx, __shfl_xor(mx, 32));                                  \
        if (!__all(mx - m_r[mi_] <= 8.0f)) {                                 \
            float mnew = fmaxf(m_r[mi_], mx);                                \
            float alpha = __builtin_amdgcn_exp2f(m_r[mi_] - mnew);           \
            m_r[mi_] = mnew;                                                 \
            l_r[mi_] *= alpha;                                               \
            _Pragma("unroll")                                                \
            for (int hi = 0; hi < 8; ++hi) o[mi_][hi] *= alpha;              \
        }                                                                    \
        const float mcur = m_r[mi_];                                         \
        float rs = 0.f;                                                      \
        _Pragma("unroll")                                                    \
        for (int ni = 0; ni < 2; ++ni) {                                     \
            float p0 = __builtin_amdgcn_exp2f(sarr[ni][0] - mcur);           \
            float p1 = __builtin_amdgcn_exp2f(sarr[ni][1] - mcur);           \
            float p2 = __builtin_amdgcn_exp2f(sarr[ni][2] - mcur);           \
            float p3 = __builtin_amdgcn_exp2f(sarr[ni][3] - mcur);           \
            rs += (p0 + p1) + (p2 + p3);                                     \
            pk_[ni][0] = pkbf(p0, p1);                                       \
            pk_[ni][1] = pkbf(p2, p3);                                       \
        }                                                                    \
        rs += __shfl_xor(rs, 16);                                            \
        rs += __shfl_xor(rs, 32);                                            \
        l_r[mi_] += rs;                                                      \
    }

#define BPERM(pk_, pT_)                                                      \
    {                                                                        \
        union { unsigned int u[4]; short8 s8; } pt;                          \
        unsigned int a0 = (unsigned)__builtin_amdgcn_ds_bpermute(bpa0, (int)pk_[0][0]); \
        unsigned int b0 = (unsigned)__builtin_amdgcn_ds_bpermute(bpa0, (int)pk_[1][0]); \
        pt.u[0] = (quad < 2) ? a0 : b0;                                      \
        unsigned int a1 = (unsigned)__builtin_amdgcn_ds_bpermute(bpa0, (int)pk_[0][1]); \
        unsigned int b1 = (unsigned)__builtin_amdgcn_ds_bpermute(bpa0, (int)pk_[1][1]); \
        pt.u[1] = (quad < 2) ? a1 : b1;                                      \
        unsigned int a2 = (unsigned)__builtin_amdgcn_ds_bpermute(bpa1, (int)pk_[0][0]); \
        unsigned int b2 = (unsigned)__builtin_amdgcn_ds_bpermute(bpa1, (int)pk_[1][0]); \
        pt.u[2] = (quad < 2) ? a2 : b2;                                      \
        unsigned int a3 = (unsigned)__builtin_amdgcn_ds_bpermute(bpa1, (int)pk_[0][1]); \
        unsigned int b3 = (unsigned)__builtin_amdgcn_ds_bpermute(bpa1, (int)pk_[1][1]); \
        pt.u[3] = (quad < 2) ? a3 : b3;                                      \
        pT_ = pt.s8;                                                         \
    }

    STAGE_KV(b, kv, 0);
    CTX_INIT(b, qt);
    int cur = 0;

    for (int it = start; it < iend; ++it) {
        const bool more = (it + 1 < iend);
        // incremental advance (replaces per-iter decomp: no sqrt/div/while)
        int b2 = b, qt2 = qt, kv2 = kv + 1;
        const bool ctxend = (kv2 == 4 * qt + 4);
        if (ctxend) { kv2 = 0; ++qt2; if (qt2 == 32) { qt2 = 0; ++b2; } }

        __syncthreads();                     // buf[cur] staged; prev reads retired
        if (more) STAGE_KV(b2, kv2, cur ^ 1);

        const int key0 = kv * 32;
        if (key0 <= qrow0 + 31) {            // skip fully-masked tiles (wave-local)
            // ---- S^T = K Q^T : D[key][qrow], lane=qrow, regs=keys ----
            f32x4 s0[2], s1[2];
#pragma unroll
            for (int ni = 0; ni < 2; ++ni) { s0[ni] = (f32x4){0.f,0.f,0.f,0.f}; s1[ni] = (f32x4){0.f,0.f,0.f,0.f}; }
            __builtin_amdgcn_s_setprio(1);
#pragma unroll
            for (int kh = 0; kh < 4; ++kh) {
#pragma unroll
                for (int ni = 0; ni < 2; ++ni) {
                    short8 kf = *(const short8*)&Ks[cur][(ni * 16 + l15) * 128 + (((kh * 4 + quad) ^ l15) << 3)];
                    s0[ni] = __builtin_amdgcn_mfma_f32_16x16x32_bf16(kf, qf[0][kh], s0[ni], 0, 0, 0);
                    s1[ni] = __builtin_amdgcn_mfma_f32_16x16x32_bf16(kf, qf[1][kh], s1[ni], 0, 0, 0);
                }
            }
            __builtin_amdgcn_s_setprio(0);
            // ---- causal mask (diagonal tiles only) ----
            if (key0 + 31 > qrow0) {
#pragma unroll
                for (int ni = 0; ni < 2; ++ni)
#pragma unroll
                    for (int j = 0; j < 4; ++j) {
                        int key = key0 + ni * 16 + quad * 4 + j;
                        if (key > qrow0 + l15)      s0[ni][j] = -1e30f;
                        if (key > qrow0 + 16 + l15) s1[ni][j] = -1e30f;
                    }
            }
            // ---- pipelined softmax/bperm: smax0 -> bp0 -> smax1 -> bp1 ----
            unsigned int pk0[2][2], pk1[2][2];
            short8 pT0, pT1;
            SMAX(s0, 0, pk0)
            BPERM(pk0, pT0)
            SMAX(s1, 1, pk1)
            BPERM(pk1, pT1)
            // ---- O^T += V^T P^T (vf shared across both halves) ----
            __builtin_amdgcn_s_setprio(1);
#pragma unroll
            for (int hi = 0; hi < 8; ++hi) {
                short8 vf = *(const short8*)&Vs[cur][(hi * 16 + l15) * 32 + ((quad ^ (l15 >> 2)) << 3)];
                o[0][hi] = __builtin_amdgcn_mfma_f32_16x16x32_bf16(vf, pT0, o[0][hi], 0, 0, 0);
                o[1][hi] = __builtin_amdgcn_mfma_f32_16x16x32_bf16(vf, pT1, o[1][hi], 0, 0, 0);
            }
            __builtin_amdgcn_s_setprio(0);
        }

        // ---- context end? flush segment, start next ----
        if (ctxend || !more) {
            CTX_FLUSH();
            if (more && ctxend) CTX_INIT(b2, qt2);
        }
        b = b2; qt = qt2; kv = kv2;
        cur ^= 1;
    }
#undef STAGE_KV
#undef CTX_INIT
#undef CTX_FLUSH
#undef SMAX
#undef BPERM
}

// ---------------------------------------------------------------------------
// merge: combine 1..7 fp32 segments per row: out = sum w_j O_j / sum w_j l_j,
// w_j = exp2(m_j - max_j m_j). Seg 0 lives in out (in-place), j>=1 in Oseg.
// ---------------------------------------------------------------------------
__global__ __launch_bounds__(256) void merge_kernel(
    float* __restrict__ out, const float* __restrict__ Oseg,
    const float2* __restrict__ ml)
{
    int idx = blockIdx.x * 256 + threadIdx.x;   // < NROWS*32
    int row = idx >> 5;
    int hc  = (idx & 31) << 2;
    int b = row >> 12, t = row & 4095, qt = t >> 7, rr = t & 127;
    int I0   = b * 2112 + 2 * qt * (qt + 1);
    int n    = 4 * (qt + 1);
    int nseg = (I0 + n - 1) / 22 - I0 / 22 + 1;   // 1..7

    const float2* mlp = ml + ((size_t)(b * 32 + qt) * 7) * 128 + rr;
    float2 s0 = mlp[0];
    float M = s0.x;
    for (int j = 1; j < nseg; ++j) M = fmaxf(M, mlp[(size_t)j * 128].x);

    float w0 = __builtin_amdgcn_exp2f(s0.x - M);
    float L  = w0 * s0.y;
    f32x4 a = *(const f32x4*)&out[(size_t)row * HD + hc];
    a = a * w0;
    for (int j = 1; j < nseg; ++j) {
        float2 mj = mlp[(size_t)j * 128];
        float w = __builtin_amdgcn_exp2f(mj.x - M);
        L += w * mj.y;
        const float* sp = Oseg + ((size_t)(b * 112 + base1(qt) + j - 1) * 128 + rr) * HD + hc;
        f32x4 sv = *(const f32x4*)sp;
        a = a + sv * w;
    }
    float inv = 1.0f / L;
    *(f32x4*)&out[(size_t)row * HD + hc] = a * inv;
}

// ---------------------------------------------------------------------------
extern "C" void kernel_launch(void* const* d_in, const int* in_sizes, int n_in,
                              void* d_out, int out_size, void* d_ws, size_t ws_size,
                              hipStream_t stream) {
    const float* x  = (const float*)d_in[0];
    const float* Wq = (const float*)d_in[1];
    const float* bq = (const float*)d_in[2];
    const float* Wk = (const float*)d_in[3];
    const float* bk = (const float*)d_in[4];
    const float* Wv = (const float*)d_in[5];
    const float* bv = (const float*)d_in[6];
    float* out = (float*)d_out;

    // ws: wt 768K | biasc 1.5K | qb 8.39M | kb 8.39M | vtb 8.39M |
    //     Oseg 896 slots x 128 x 128 f32 = 58.7M | ml 1.84M  (~86.5 MB total)
    unsigned short* wt    = (unsigned short*)d_ws;
    float*          biasc = (float*)((char*)d_ws + 786432);
    unsigned short* qb    = (unsigned short*)((char*)d_ws + 787968);
    unsigned short* kb    = qb  + (size_t)NROWS * HD;
    unsigned short* vtb   = kb  + (size_t)NROWS * HD;
    float*          Oseg  = (float*)((char*)d_ws + 787968 + 3ull * NROWS * HD * 2);
    float2*         mlseg = (float2*)((char*)Oseg + 896ull * 128 * HD * 4);

    prep_kernel<<<dim3(384), 256, 0, stream>>>(Wq, bq, Wk, bk, Wv, bv, wt, biasc);
    gemm_qkv<<<dim3(256), 768, 0, stream>>>(x, wt, biasc, qb, kb, vtb);
    attn_kernel<<<dim3(768), 256, 0, stream>>>(qb, kb, vtb, out, Oseg, mlseg);
    merge_kernel<<<dim3(NROWS * 32 / 256), 256, 0, stream>>>(out, Oseg, mlseg);
}

// Round 6
// 308.797 us; speedup vs baseline: 1.1711x; 1.1711x over previous
//
#include <hip/hip_runtime.h>
#include <hip/hip_bf16.h>
#include <stdint.h>

#define BATCH 8
#define SEQ   4096
#define EMB   1024
#define HD    128
#define NROWS 32768

typedef __attribute__((ext_vector_type(8))) short short8;
typedef __attribute__((ext_vector_type(4))) float f32x4;

__device__ inline unsigned short f2bf(float f) {
    union { float f; unsigned int u; } c; c.f = f;
    unsigned int u = c.u;
    unsigned int r = (u + 0x7fffu + ((u >> 16) & 1u)) >> 16;
    return (unsigned short)r;
}
__device__ inline float bf2f(unsigned short u) {
    union { unsigned int i; float f; } c; c.i = ((unsigned int)u) << 16; return c.f;
}
__device__ inline unsigned int pkbf(float a, float b) {
    __hip_bfloat162 h = __float22bfloat162_rn(make_float2(a, b));
    union { __hip_bfloat162 h; unsigned int u; } c; c.h = h; return c.u;
}

#define GLDS16(gp, lp) __builtin_amdgcn_global_load_lds( \
    (const __attribute__((address_space(1))) void*)(gp), \
    (__attribute__((address_space(3))) void*)(lp), 16, 0, 0)

// ---- stream-K work decomposition (32-key items) ---------------------------
// item = (b, qt, kv32); per batch: sum_qt 4(qt+1) = 2112; total 16896.
// 768 blocks x exactly 22 items. chunk = (rank&7)*96 + rank/8 -> each XCD
// owns exactly one batch (K+V+Q ~3MB, L2-resident).
__device__ inline void decomp(int it, int& b, int& qt, int& kv) {
    b = it / 2112;
    int r = it - b * 2112;
    int q = (int)((__builtin_sqrtf(2.0f * (float)r + 1.0f) - 1.0f) * 0.5f);
    while (2 * (q + 1) * (q + 2) <= r) ++q;
    while (2 * q * (q + 1) > r) --q;
    qt = q;
    kv = r - 2 * q * (q + 1);
}
// overflow-slot base per batch; seg-width bands; 112/batch
__device__ inline int base1(int qt) {
    if (qt < 5)  return qt;
    if (qt < 11) return 5 + 2 * (qt - 5);
    if (qt < 16) return 17 + 3 * (qt - 11);
    if (qt < 22) return 32 + 4 * (qt - 16);
    if (qt < 27) return 56 + 5 * (qt - 22);
    return 81 + 6 * (qt - 27);
}

// ---------------------------------------------------------------------------
// prep: wt[n][k] = bf16(W[k][h]) for n = sel*128+h. 384 blocks, one row each.
// ---------------------------------------------------------------------------
__global__ __launch_bounds__(256) void prep_kernel(
    const float* __restrict__ Wq, const float* __restrict__ bq,
    const float* __restrict__ Wk, const float* __restrict__ bk,
    const float* __restrict__ Wv, const float* __restrict__ bv,
    unsigned short* __restrict__ wt, float* __restrict__ biasc)
{
    const int n = blockIdx.x;           // 0..383
    const int sel = n >> 7, h = n & 127;
    const float* W = (sel == 0) ? Wq : (sel == 1) ? Wk : Wv;
    const int tid = threadIdx.x;
    const int k0 = tid * 4;
    union { unsigned short us[4]; uint2 v; } pk;
#pragma unroll
    for (int u = 0; u < 4; ++u) pk.us[u] = f2bf(W[(size_t)(k0 + u) * HD + h]);
    *(uint2*)&wt[(size_t)n * EMB + k0] = pk.v;
    if (tid == 0) {
        const float* bp = (sel == 0) ? bq : (sel == 1) ? bk : bv;
        biasc[n] = bp[h];
    }
}

// ---------------------------------------------------------------------------
// gemm_qkv v2: fused QKV. 256 blocks x 128 rows x all 384 cols; 12 waves
// (768 thr), wave tile 64 rows x 64 cols, acc[4][4].
// ---------------------------------------------------------------------------
__global__ __launch_bounds__(768, 3) void gemm_qkv(
    const float* __restrict__ x, const unsigned short* __restrict__ wt,
    const float* __restrict__ biasc,
    unsigned short* __restrict__ q, unsigned short* __restrict__ kOut,
    unsigned short* __restrict__ vt)
{
    const int m0  = blockIdx.x * 128;
    const int tid = threadIdx.x;
    const int wave = tid >> 6, lane = tid & 63;
    const int quad = lane >> 4, l15 = lane & 15;
    const int wm = (wave >= 6) ? 1 : 0;      // 2 M-waves x 6 N-waves
    const int wn = wave - wm * 6;            // 0..5, 64 cols each

    __shared__ __align__(16) unsigned short As[2][128][40];   // +8 pad
    __shared__ __align__(16) unsigned short Bs[2][12288];     // [384][32] swizzled

    f32x4 acc[4][4];
#pragma unroll
    for (int i = 0; i < 4; ++i)
#pragma unroll
        for (int j = 0; j < 4; ++j) acc[i][j] = (f32x4){0.f, 0.f, 0.f, 0.f};

    const int aactive = (tid < 512);
    const int arow = tid >> 3, akc = (tid & 7) * 4;
    float4 aR0, aR1;

#define LOAD_A(kt)                                                          \
    if (aactive) {                                                          \
        aR0 = *(const float4*)(x + (size_t)(m0 + arow) * EMB + (kt) * 32 + akc);        \
        aR1 = *(const float4*)(x + (size_t)(m0 + arow + 64) * EMB + (kt) * 32 + akc);   \
    }
#define WRITE_A(buf)                                                        \
    if (aactive) {                                                          \
        union { unsigned short us[4]; uint2 v; } p0, p1;                    \
        p0.us[0] = f2bf(aR0.x); p0.us[1] = f2bf(aR0.y);                     \
        p0.us[2] = f2bf(aR0.z); p0.us[3] = f2bf(aR0.w);                     \
        *(uint2*)&As[buf][arow][akc] = p0.v;                                \
        p1.us[0] = f2bf(aR1.x); p1.us[1] = f2bf(aR1.y);                     \
        p1.us[2] = f2bf(aR1.z); p1.us[3] = f2bf(aR1.w);                     \
        *(uint2*)&As[buf][arow + 64][akc] = p1.v;                           \
    }
#define STAGE_B(kt, buf)                                                    \
    {                                                                       \
        _Pragma("unroll")                                                   \
        for (int g = 0; g < 2; ++g) {                                       \
            int s0 = (g * 12 + wave) * 64;                                  \
            int s  = s0 + lane;                                             \
            int n  = s >> 2, c = (s & 3) ^ (n & 3);                         \
            GLDS16(wt + (size_t)n * EMB + (kt) * 32 + c * 8,                \
                   &Bs[buf][s0 * 8]);                                       \
        }                                                                   \
    }

    LOAD_A(0); STAGE_B(0, 0); WRITE_A(0);
    int cur = 0;

    for (int kt = 0; kt < 32; ++kt) {
        __syncthreads();
        if (kt < 31) { LOAD_A(kt + 1); STAGE_B(kt + 1, cur ^ 1); }
        short8 af[4], bw[4];
#pragma unroll
        for (int mj = 0; mj < 4; ++mj)
            af[mj] = *(const short8*)&As[cur][wm * 64 + mj * 16 + l15][quad * 8];
#pragma unroll
        for (int ni = 0; ni < 4; ++ni) {
            int n = wn * 64 + ni * 16 + l15;
            bw[ni] = *(const short8*)&Bs[cur][n * 32 + ((quad ^ (n & 3)) << 3)];
        }
#pragma unroll
        for (int ni = 0; ni < 4; ++ni)
#pragma unroll
            for (int mj = 0; mj < 4; ++mj)
                acc[ni][mj] = __builtin_amdgcn_mfma_f32_16x16x32_bf16(
                    bw[ni], af[mj], acc[ni][mj], 0, 0, 0);
        if (kt < 31) WRITE_A(cur ^ 1);
        cur ^= 1;
    }

    const float qscale = 0.08838834764831845f * 1.4426950408889634f;
    const int bb = m0 >> 12;
    const int t0 = m0 & 4095;
    const int mrow0 = m0 + wm * 64;
    const int tl0   = t0 + wm * 64;
#pragma unroll
    for (int ni = 0; ni < 4; ++ni) {
        int colbase = wn * 64 + ni * 16;
        int sel = colbase >> 7;
        int c0 = colbase + quad * 4;
        float4 bv4 = *(const float4*)&biasc[c0];
#pragma unroll
        for (int mj = 0; mj < 4; ++mj) {
            int m = mrow0 + mj * 16 + l15;
            if (sel == 0) {
                union { unsigned short us[4]; uint2 v; } pk;
#pragma unroll
                for (int j = 0; j < 4; ++j)
                    pk.us[j] = f2bf((acc[ni][mj][j] + ((const float*)&bv4)[j]) * qscale);
                *(uint2*)&q[(size_t)m * HD + (c0 & 127)] = pk.v;
            } else if (sel == 1) {
                union { unsigned short us[4]; uint2 v; } pk;
#pragma unroll
                for (int j = 0; j < 4; ++j)
                    pk.us[j] = f2bf(acc[ni][mj][j] + ((const float*)&bv4)[j]);
                *(uint2*)&kOut[(size_t)m * HD + (c0 & 127)] = pk.v;
            } else {
#pragma unroll
                for (int j = 0; j < 4; ++j) {
                    int h = (c0 & 127) + j;
                    vt[((size_t)(bb * 128 + h)) * SEQ + tl0 + mj * 16 + l15] =
                        f2bf(acc[ni][mj][j] + ((const float*)&bv4)[j]);
                }
            }
        }
    }
#undef LOAD_A
#undef WRITE_A
#undef STAGE_B
}

// ---------------------------------------------------------------------------
// attn v6: stream-K flash attention, 32-key items, 768 blocks x 256 thr.
// = v5 with __launch_bounds__(256,3) restored. v5's (256,4) capped arch-VGPR
// at 64 -> scratch spills (+50MB FETCH & WRITE per dispatch, VALUBusy 26->20,
// attn 73->128us). 3 contexts/SIMD with VGPR~108 and zero spill is the
// proven optimum for this context size. Keeps v5's clean wins: incremental
// (b,qt,kv) advance (no per-iter sqrt/div) and pipelined smax0->bp0->
// smax1->bp1 softmax.
// ---------------------------------------------------------------------------
__global__ __launch_bounds__(256, 3) void attn_kernel(
    const unsigned short* __restrict__ q, const unsigned short* __restrict__ k,
    const unsigned short* __restrict__ vt, float* __restrict__ out,
    float* __restrict__ Oseg, float2* __restrict__ ml)
{
    const int rank  = blockIdx.x;                       // 0..767
    const int chunk = (rank & 7) * 96 + (rank >> 3);    // XCD-contiguous
    const int start = chunk * 22;
    const int iend  = start + 22;

    const int tid  = threadIdx.x;
    const int wave = tid >> 6, lane = tid & 63;
    const int quad = lane >> 4, l15 = lane & 15;

    __shared__ __align__(16) unsigned short Ks[2][4096];  // [32 key][16 ch8 sw]
    __shared__ __align__(16) unsigned short Vs[2][4096];  // [128 h][4 ch8 sw]

    const int bpa0 = (l15 + 16 * ((2 * quad) & 3)) * 4;   // bpermute byte addrs
    const int bpa1 = (l15 + 16 * ((2 * quad + 1) & 3)) * 4;

#define STAGE_KV(b_, kv_, buf_)                                              \
    {                                                                        \
        const size_t kb0 = (size_t)(b_) * SEQ + (kv_) * 32;                  \
        const size_t vb0 = (size_t)(b_) * HD * SEQ + (kv_) * 32;             \
        _Pragma("unroll")                                                    \
        for (int g = 0; g < 2; ++g) {                                        \
            int s0 = (g * 4 + wave) * 64;                                    \
            int s  = s0 + lane;                                              \
            int key = s >> 4, c = (s & 15) ^ (key & 15);                     \
            GLDS16(k + (kb0 + key) * HD + c * 8, &Ks[buf_][s0 * 8]);         \
        }                                                                    \
        _Pragma("unroll")                                                    \
        for (int g = 0; g < 2; ++g) {                                        \
            int s0 = (g * 4 + wave) * 64;                                    \
            int s  = s0 + lane;                                              \
            int h = s >> 2, c = (s & 3) ^ ((h >> 2) & 3);                    \
            GLDS16(vt + vb0 + (size_t)h * SEQ + c * 8, &Vs[buf_][s0 * 8]);   \
        }                                                                    \
    }

    int b, qt, kv;
    decomp(start, b, qt, kv);

    short8 qf[2][4];
    f32x4  o[2][8];
    float  m_r[2], l_r[2];
    int    qrow0 = 0;

#define CTX_INIT(b_, q_)                                                     \
    {                                                                        \
        qrow0 = (q_) * 128 + wave * 32;                                      \
        const size_t qoff = (size_t)(b_) * SEQ + qrow0;                      \
        _Pragma("unroll")                                                    \
        for (int mi = 0; mi < 2; ++mi)                                       \
            _Pragma("unroll")                                                \
            for (int kh = 0; kh < 4; ++kh)                                   \
                qf[mi][kh] = *(const short8*)(q + (qoff + mi * 16 + l15) * HD + kh * 32 + quad * 8); \
        _Pragma("unroll")                                                    \
        for (int mi = 0; mi < 2; ++mi) {                                     \
            _Pragma("unroll")                                                \
            for (int hi = 0; hi < 8; ++hi) o[mi][hi] = (f32x4){0.f, 0.f, 0.f, 0.f}; \
            m_r[mi] = -1e30f; l_r[mi] = 0.f;                                 \
        }                                                                    \
    }

#define CTX_FLUSH()                                                          \
    {                                                                        \
        const int I0 = b * 2112 + 2 * qt * (qt + 1);                         \
        const int j  = chunk - I0 / 22;                                      \
        const int rr = wave * 32;                                            \
        float* obase;                                                        \
        if (j == 0) obase = out + ((size_t)b * SEQ + qrow0) * HD;            \
        else obase = Oseg + ((size_t)(b * 112 + base1(qt) + j - 1) * 128 + rr) * HD; \
        const size_t mlb = ((size_t)(b * 32 + qt) * 7 + j) * 128 + rr;       \
        _Pragma("unroll")                                                    \
        for (int mi = 0; mi < 2; ++mi) {                                     \
            if (quad == 0) ml[mlb + mi * 16 + l15] = make_float2(m_r[mi], l_r[mi]); \
            _Pragma("unroll")                                                \
            for (int hi = 0; hi < 8; ++hi)                                   \
                *(f32x4*)&obase[(size_t)(mi * 16 + l15) * HD + hi * 16 + quad * 4] = o[mi][hi]; \
        }                                                                    \
    }

// wave-parallel softmax for one mi half; writes pk_, updates m_r/l_r/o
#define SMAX(sarr, mi_, pk_)                                                 \
    {                                                                        \
        float mx = fmaxf(fmaxf(fmaxf(sarr[0][0], sarr[0][1]),               \
                               fmaxf(sarr[0][2], sarr[0][3])),              \
                         fmaxf(fmaxf(sarr[1][0], sarr[1][1]),               \
                               fmaxf(sarr[1][2], sarr[1][3])));             \
        mx = fmaxf(mx, __shfl_xor(mx, 16));                                  \
        mx = fmaxf(mx, __shfl_xor(mx, 32));                                  \
        if (!__all(mx - m_r[mi_] <= 8.0f)) {                                 \
            float mnew = fmaxf(m_r[mi_], mx);                                \
            float alpha = __builtin_amdgcn_exp2f(m_r[mi_] - mnew);           \
            m_r[mi_] = mnew;                                                 \
            l_r[mi_] *= alpha;                                               \
            _Pragma("unroll")                                                \
            for (int hi = 0; hi < 8; ++hi) o[mi_][hi] *= alpha;              \
        }                                                                    \
        const float mcur = m_r[mi_];                                         \
        float rs = 0.f;                                                      \
        _Pragma("unroll")                                                    \
        for (int ni = 0; ni < 2; ++ni) {                                     \
            float p0 = __builtin_amdgcn_exp2f(sarr[ni][0] - mcur);           \
            float p1 = __builtin_amdgcn_exp2f(sarr[ni][1] - mcur);           \
            float p2 = __builtin_amdgcn_exp2f(sarr[ni][2] - mcur);           \
            float p3 = __builtin_amdgcn_exp2f(sarr[ni][3] - mcur);           \
            rs += (p0 + p1) + (p2 + p3);                                     \
            pk_[ni][0] = pkbf(p0, p1);                                       \
            pk_[ni][1] = pkbf(p2, p3);                                       \
        }                                                                    \
        rs += __shfl_xor(rs, 16);                                            \
        rs += __shfl_xor(rs, 32);                                            \
        l_r[mi_] += rs;                                                      \
    }

#define BPERM(pk_, pT_)                                                      \
    {                                                                        \
        union { unsigned int u[4]; short8 s8; } pt;                          \
        unsigned int a0 = (unsigned)__builtin_amdgcn_ds_bpermute(bpa0, (int)pk_[0][0]); \
        unsigned int b0 = (unsigned)__builtin_amdgcn_ds_bpermute(bpa0, (int)pk_[1][0]); \
        pt.u[0] = (quad < 2) ? a0 : b0;                                      \
        unsigned int a1 = (unsigned)__builtin_amdgcn_ds_bpermute(bpa0, (int)pk_[0][1]); \
        unsigned int b1 = (unsigned)__builtin_amdgcn_ds_bpermute(bpa0, (int)pk_[1][1]); \
        pt.u[1] = (quad < 2) ? a1 : b1;                                      \
        unsigned int a2 = (unsigned)__builtin_amdgcn_ds_bpermute(bpa1, (int)pk_[0][0]); \
        unsigned int b2 = (unsigned)__builtin_amdgcn_ds_bpermute(bpa1, (int)pk_[1][0]); \
        pt.u[2] = (quad < 2) ? a2 : b2;                                      \
        unsigned int a3 = (unsigned)__builtin_amdgcn_ds_bpermute(bpa1, (int)pk_[0][1]); \
        unsigned int b3 = (unsigned)__builtin_amdgcn_ds_bpermute(bpa1, (int)pk_[1][1]); \
        pt.u[3] = (quad < 2) ? a3 : b3;                                      \
        pT_ = pt.s8;                                                         \
    }

    STAGE_KV(b, kv, 0);
    CTX_INIT(b, qt);
    int cur = 0;

    for (int it = start; it < iend; ++it) {
        const bool more = (it + 1 < iend);
        // incremental advance (no sqrt/div/while on the critical path)
        int b2 = b, qt2 = qt, kv2 = kv + 1;
        const bool ctxend = (kv2 == 4 * qt + 4);
        if (ctxend) { kv2 = 0; ++qt2; if (qt2 == 32) { qt2 = 0; ++b2; } }

        __syncthreads();                     // buf[cur] staged; prev reads retired
        if (more) STAGE_KV(b2, kv2, cur ^ 1);

        const int key0 = kv * 32;
        if (key0 <= qrow0 + 31) {            // skip fully-masked tiles (wave-local)
            // ---- S^T = K Q^T : D[key][qrow], lane=qrow, regs=keys ----
            f32x4 s0[2], s1[2];
#pragma unroll
            for (int ni = 0; ni < 2; ++ni) { s0[ni] = (f32x4){0.f,0.f,0.f,0.f}; s1[ni] = (f32x4){0.f,0.f,0.f,0.f}; }
            __builtin_amdgcn_s_setprio(1);
#pragma unroll
            for (int kh = 0; kh < 4; ++kh) {
#pragma unroll
                for (int ni = 0; ni < 2; ++ni) {
                    short8 kf = *(const short8*)&Ks[cur][(ni * 16 + l15) * 128 + (((kh * 4 + quad) ^ l15) << 3)];
                    s0[ni] = __builtin_amdgcn_mfma_f32_16x16x32_bf16(kf, qf[0][kh], s0[ni], 0, 0, 0);
                    s1[ni] = __builtin_amdgcn_mfma_f32_16x16x32_bf16(kf, qf[1][kh], s1[ni], 0, 0, 0);
                }
            }
            __builtin_amdgcn_s_setprio(0);
            // ---- causal mask (diagonal tiles only) ----
            if (key0 + 31 > qrow0) {
#pragma unroll
                for (int ni = 0; ni < 2; ++ni)
#pragma unroll
                    for (int j = 0; j < 4; ++j) {
                        int key = key0 + ni * 16 + quad * 4 + j;
                        if (key > qrow0 + l15)      s0[ni][j] = -1e30f;
                        if (key > qrow0 + 16 + l15) s1[ni][j] = -1e30f;
                    }
            }
            // ---- pipelined softmax/bperm: smax0 -> bp0 -> smax1 -> bp1 ----
            unsigned int pk0[2][2], pk1[2][2];
            short8 pT0, pT1;
            SMAX(s0, 0, pk0)
            BPERM(pk0, pT0)
            SMAX(s1, 1, pk1)
            BPERM(pk1, pT1)
            // ---- O^T += V^T P^T (vf shared across both halves) ----
            __builtin_amdgcn_s_setprio(1);
#pragma unroll
            for (int hi = 0; hi < 8; ++hi) {
                short8 vf = *(const short8*)&Vs[cur][(hi * 16 + l15) * 32 + ((quad ^ (l15 >> 2)) << 3)];
                o[0][hi] = __builtin_amdgcn_mfma_f32_16x16x32_bf16(vf, pT0, o[0][hi], 0, 0, 0);
                o[1][hi] = __builtin_amdgcn_mfma_f32_16x16x32_bf16(vf, pT1, o[1][hi], 0, 0, 0);
            }
            __builtin_amdgcn_s_setprio(0);
        }

        // ---- context end? flush segment, start next ----
        if (ctxend || !more) {
            CTX_FLUSH();
            if (more && ctxend) CTX_INIT(b2, qt2);
        }
        b = b2; qt = qt2; kv = kv2;
        cur ^= 1;
    }
#undef STAGE_KV
#undef CTX_INIT
#undef CTX_FLUSH
#undef SMAX
#undef BPERM
}

// ---------------------------------------------------------------------------
// merge: combine 1..7 fp32 segments per row: out = sum w_j O_j / sum w_j l_j,
// w_j = exp2(m_j - max_j m_j). Seg 0 lives in out (in-place), j>=1 in Oseg.
// ---------------------------------------------------------------------------
__global__ __launch_bounds__(256) void merge_kernel(
    float* __restrict__ out, const float* __restrict__ Oseg,
    const float2* __restrict__ ml)
{
    int idx = blockIdx.x * 256 + threadIdx.x;   // < NROWS*32
    int row = idx >> 5;
    int hc  = (idx & 31) << 2;
    int b = row >> 12, t = row & 4095, qt = t >> 7, rr = t & 127;
    int I0   = b * 2112 + 2 * qt * (qt + 1);
    int n    = 4 * (qt + 1);
    int nseg = (I0 + n - 1) / 22 - I0 / 22 + 1;   // 1..7

    const float2* mlp = ml + ((size_t)(b * 32 + qt) * 7) * 128 + rr;
    float2 s0 = mlp[0];
    float M = s0.x;
    for (int j = 1; j < nseg; ++j) M = fmaxf(M, mlp[(size_t)j * 128].x);

    float w0 = __builtin_amdgcn_exp2f(s0.x - M);
    float L  = w0 * s0.y;
    f32x4 a = *(const f32x4*)&out[(size_t)row * HD + hc];
    a = a * w0;
    for (int j = 1; j < nseg; ++j) {
        float2 mj = mlp[(size_t)j * 128];
        float w = __builtin_amdgcn_exp2f(mj.x - M);
        L += w * mj.y;
        const float* sp = Oseg + ((size_t)(b * 112 + base1(qt) + j - 1) * 128 + rr) * HD + hc;
        f32x4 sv = *(const f32x4*)sp;
        a = a + sv * w;
    }
    float inv = 1.0f / L;
    *(f32x4*)&out[(size_t)row * HD + hc] = a * inv;
}

// ---------------------------------------------------------------------------
extern "C" void kernel_launch(void* const* d_in, const int* in_sizes, int n_in,
                              void* d_out, int out_size, void* d_ws, size_t ws_size,
                              hipStream_t stream) {
    const float* x  = (const float*)d_in[0];
    const float* Wq = (const float*)d_in[1];
    const float* bq = (const float*)d_in[2];
    const float* Wk = (const float*)d_in[3];
    const float* bk = (const float*)d_in[4];
    const float* Wv = (const float*)d_in[5];
    const float* bv = (const float*)d_in[6];
    float* out = (float*)d_out;

    // ws: wt 768K | biasc 1.5K | qb 8.39M | kb 8.39M | vtb 8.39M |
    //     Oseg 896 slots x 128 x 128 f32 = 58.7M | ml 1.84M  (~86.5 MB total)
    unsigned short* wt    = (unsigned short*)d_ws;
    float*          biasc = (float*)((char*)d_ws + 786432);
    unsigned short* qb    = (unsigned short*)((char*)d_ws + 787968);
    unsigned short* kb    = qb  + (size_t)NROWS * HD;
    unsigned short* vtb   = kb  + (size_t)NROWS * HD;
    float*          Oseg  = (float*)((char*)d_ws + 787968 + 3ull * NROWS * HD * 2);
    float2*         mlseg = (float2*)((char*)Oseg + 896ull * 128 * HD * 4);

    prep_kernel<<<dim3(384), 256, 0, stream>>>(Wq, bq, Wk, bk, Wv, bv, wt, biasc);
    gemm_qkv<<<dim3(256), 768, 0, stream>>>(x, wt, biasc, qb, kb, vtb);
    attn_kernel<<<dim3(768), 256, 0, stream>>>(qb, kb, vtb, out, Oseg, mlseg);
    merge_kernel<<<dim3(NROWS * 32 / 256), 256, 0, stream>>>(out, Oseg, mlseg);
}